// Round 12
// baseline (852.509 us; speedup 1.0000x reference)
//
#include <hip/hip_runtime.h>
#include <hip/hip_bf16.h>

#define BB 512
#define TT 256

typedef __attribute__((ext_vector_type(8))) short bf16x8;
typedef __attribute__((ext_vector_type(4))) float f32x4;

__device__ __forceinline__ unsigned short f2b(float f) {
    union { float f; unsigned u; } v; v.f = f;
    unsigned r = v.u + 0x7FFFu + ((v.u >> 16) & 1u);
    return (unsigned short)(r >> 16);
}
__device__ __forceinline__ float b2f(unsigned short h) {
    union { unsigned u; float f; } v; v.u = ((unsigned)h) << 16;
    return v.f;
}
// packed f32x2 -> bf16x2 (v_cvt_pk_bf16_f32, RNE — bit-compatible with f2b)
__device__ __forceinline__ ushort2 pk2(float a, float b) {
    __hip_bfloat162 h = __float22bfloat162_rn(float2{a, b});
    union { __hip_bfloat162 h; ushort2 u; } v; v.h = h; return v.u;
}

// ======================================================================
// B-layout (per (s,t) 16-batch x K block of shorts):
//   addr(b,k) = (k>>3)*128 + b*8 + (k&7)
//   B-frag (k-chunk kc) = ONE b128 at kc*512 + quad*128 + l15*8
//   D-tile (col-tile mt) write = ushort4 at wro + mt*256,
//     wro = ((colbase>>3)+(quad>>1))*128 + l15*8 + (quad&1)*4
// ======================================================================

// ---------------- fp32 x -> bf16 B-layout tiles ----------------
__global__ __launch_bounds__(256) void cvt_tile(const float* __restrict__ x,
                                                unsigned short* __restrict__ xb) {
    const int blk = blockIdx.x;            // s*256 + t
    const int s = blk >> 8, t = blk & 255;
    const int tid = threadIdx.x;
    const int b = (tid >> 1) & 15;
    const int f0 = (tid >> 5) * 8 + (tid & 1) * 4;
    float4 v = *reinterpret_cast<const float4*>(
        &x[(((size_t)(s * 16 + b) * TT) + t) * 64 + f0]);
    ushort2 lo = pk2(v.x, v.y), hi = pk2(v.z, v.w);
    ushort4 o; o.x = lo.x; o.y = lo.y; o.z = hi.x; o.w = hi.y;
    *reinterpret_cast<ushort4*>(&xb[(size_t)blk * 1024 + tid * 4]) = o;
}

// ---------------- 4-layer skewed fused RNN ----------------
// One block per batch-slice runs ALL layers, layer l at t = tau-(l-1).
// Every operand at step tau was written at step tau-1 (single LDS ping-pong,
// ONE barrier/step). Layer l's recurrent frag af_l doubles as layer l+1's
// input frag (same registers). Only x-in (global loads) and h4-out (global
// stores) touch HBM. Per-layer bias->Wx->Wh MFMA order identical to r11.
__global__ __launch_bounds__(256, 1) void rnn4(
    const unsigned short* __restrict__ Xb,
    const float* __restrict__ Wx1, const float* __restrict__ Wh1, const float* __restrict__ b1,
    const float* __restrict__ Wx2, const float* __restrict__ Wh2, const float* __restrict__ b2,
    const float* __restrict__ Wx3, const float* __restrict__ Wh3, const float* __restrict__ b3,
    const float* __restrict__ Wx4, const float* __restrict__ Wh4, const float* __restrict__ b4,
    unsigned short* __restrict__ H4) {
    const int tid = threadIdx.x;
    const int s = blockIdx.x;
    const int w = tid >> 6;
    const int lane = tid & 63;
    const int l15 = lane & 15;
    const int quad = lane >> 4;
    const int rdo = quad * 128 + l15 * 8;

    // stationary weight fragments (fp32 -> bf16, once)
    bf16x8 wh1[4][2], wx1[2][2];   // L1: H=128, KX=64
    bf16x8 wh2[8][4], wx2[4][4];   // L2: H=256, KX=128
    bf16x8 wh3[4][2], wx3[8][2];   // L3: H=128, KX=256
    bf16x8 wh4[2][1], wx4[4][1];   // L4: H=64,  KX=128

#define LOADW(dst, KC_, MT_, Wp, H_)                                     \
    _Pragma("unroll")                                                    \
    for (int mt = 0; mt < MT_; ++mt) {                                   \
        int m = w * (H_ / 4) + mt * 16 + l15;                            \
        _Pragma("unroll")                                                \
        for (int kc = 0; kc < KC_; ++kc)                                 \
            _Pragma("unroll")                                            \
            for (int j = 0; j < 8; ++j)                                  \
                dst[kc][mt][j] = (short)f2b(Wp[(kc * 32 + quad * 8 + j) * H_ + m]); \
    }
    LOADW(wh1, 4, 2, Wh1, 128) LOADW(wx1, 2, 2, Wx1, 128)
    LOADW(wh2, 8, 4, Wh2, 256) LOADW(wx2, 4, 4, Wx2, 256)
    LOADW(wh3, 4, 2, Wh3, 128) LOADW(wx3, 8, 2, Wx3, 128)
    LOADW(wh4, 2, 1, Wh4, 64)  LOADW(wx4, 4, 1, Wx4, 64)
#undef LOADW

    f32x4 bv1[2], bv2[4], bv3[2], bv4[1];
#define LOADB(dst, MT_, bp, H_)                                          \
    _Pragma("unroll")                                                    \
    for (int mt = 0; mt < MT_; ++mt) {                                   \
        float4 t4v = reinterpret_cast<const float4*>(bp)[(w * (H_ / 4) >> 2) + mt * 4 + quad]; \
        dst[mt][0] = t4v.x; dst[mt][1] = t4v.y; dst[mt][2] = t4v.z; dst[mt][3] = t4v.w; \
    }
    LOADB(bv1, 2, b1, 128) LOADB(bv2, 4, b2, 256) LOADB(bv3, 2, b3, 128) LOADB(bv4, 1, b4, 64)
#undef LOADB

    // LDS: h1|h2|h3|h4 per parity: offsets (shorts) 0|2048|6144|8192, total 9216
    __shared__ __align__(16) unsigned short hall[2][9216];
    for (int i = tid; i < 2 * 9216; i += 256) (&hall[0][0])[i] = 0;
    __syncthreads();

    const unsigned short* Xs = Xb + (size_t)s * TT * 1024;
    unsigned short* H4s = H4 + (size_t)s * TT * 1024;

    const int wro1 = (w * 4 + (quad >> 1)) * 128 + l15 * 8 + (quad & 1) * 4;
    const int wro2 = (w * 8 + (quad >> 1)) * 128 + l15 * 8 + (quad & 1) * 4;
    const int wro3 = wro1;
    const int wro4 = (w * 2 + (quad >> 1)) * 128 + l15 * 8 + (quad & 1) * 4;

    // x parity frag buffers: A = even tau, B = odd; preloaded t=0,1; ptrs at t=2,3
    bf16x8 xA[2], xB[2];
#pragma unroll
    for (int kx = 0; kx < 2; ++kx) {
        xA[kx] = *reinterpret_cast<const bf16x8*>(&Xs[kx * 512 + rdo]);
        xB[kx] = *reinterpret_cast<const bf16x8*>(&Xs[1024 + kx * 512 + rdo]);
    }
    const unsigned short* xp0 = Xs + 2 * 1024 + rdo;
    const unsigned short* xp1 = Xs + 3 * 1024 + rdo;
    // h4 out: odd-parity macro stores t4=0,2,..; even-parity t4=1,3,..
    unsigned short* op0 = H4s + 1024 + wro4;
    unsigned short* op1 = H4s + wro4;

#define PACK_STORE(ACC, MT_, WBASE, WRO)                                     \
    _Pragma("unroll")                                                        \
    for (int mt = 0; mt < MT_; ++mt) {                                       \
        ushort2 lo = pk2(fmaxf(ACC[mt][0], 0.f), fmaxf(ACC[mt][1], 0.f));    \
        ushort2 hi = pk2(fmaxf(ACC[mt][2], 0.f), fmaxf(ACC[mt][3], 0.f));    \
        ushort4 o; o.x = lo.x; o.y = lo.y; o.z = hi.x; o.w = hi.y;           \
        *reinterpret_cast<ushort4*>(&WB[(WBASE) + (WRO) + mt * 256]) = o;    \
    }

#define STEP(TAU_, RP, WP, XBUF, XPP, OPP)                                   \
    {                                                                        \
        const int tau_ = (TAU_);                                             \
        const unsigned short* RB = &hall[RP][0];                             \
        unsigned short* WB = &hall[WP][0];                                   \
        bf16x8 af1[4], af2[8], af3[4], af4[2];                               \
        _Pragma("unroll")                                                    \
        for (int kc = 0; kc < 4; ++kc)                                       \
            af1[kc] = *reinterpret_cast<const bf16x8*>(&RB[rdo + kc * 512]); \
        _Pragma("unroll")                                                    \
        for (int kc = 0; kc < 8; ++kc)                                       \
            af2[kc] = *reinterpret_cast<const bf16x8*>(&RB[2048 + rdo + kc * 512]); \
        _Pragma("unroll")                                                    \
        for (int kc = 0; kc < 4; ++kc)                                       \
            af3[kc] = *reinterpret_cast<const bf16x8*>(&RB[6144 + rdo + kc * 512]); \
        _Pragma("unroll")                                                    \
        for (int kc = 0; kc < 2; ++kc)                                       \
            af4[kc] = *reinterpret_cast<const bf16x8*>(&RB[8192 + rdo + kc * 512]); \
        if ((unsigned)tau_ < TT) { /* L1, t=tau */                           \
            f32x4 acc[2];                                                    \
            _Pragma("unroll") for (int mt = 0; mt < 2; ++mt) acc[mt] = bv1[mt]; \
            _Pragma("unroll")                                                \
            for (int kx = 0; kx < 2; ++kx)                                   \
                _Pragma("unroll")                                            \
                for (int mt = 0; mt < 2; ++mt)                               \
                    acc[mt] = __builtin_amdgcn_mfma_f32_16x16x32_bf16(wx1[kx][mt], XBUF[kx], acc[mt], 0, 0, 0); \
            if (tau_ + 2 < TT) {                                             \
                _Pragma("unroll")                                            \
                for (int kx = 0; kx < 2; ++kx)                               \
                    XBUF[kx] = *reinterpret_cast<const bf16x8*>(&XPP[kx * 512]); \
                XPP += 2048;                                                 \
            }                                                                \
            _Pragma("unroll")                                                \
            for (int kc = 0; kc < 4; ++kc)                                   \
                _Pragma("unroll")                                            \
                for (int mt = 0; mt < 2; ++mt)                               \
                    acc[mt] = __builtin_amdgcn_mfma_f32_16x16x32_bf16(wh1[kc][mt], af1[kc], acc[mt], 0, 0, 0); \
            PACK_STORE(acc, 2, 0, wro1)                                      \
        }                                                                    \
        if ((unsigned)(tau_ - 1) < TT) { /* L2 */                            \
            f32x4 acc[4];                                                    \
            _Pragma("unroll") for (int mt = 0; mt < 4; ++mt) acc[mt] = bv2[mt]; \
            _Pragma("unroll")                                                \
            for (int kx = 0; kx < 4; ++kx)                                   \
                _Pragma("unroll")                                            \
                for (int mt = 0; mt < 4; ++mt)                               \
                    acc[mt] = __builtin_amdgcn_mfma_f32_16x16x32_bf16(wx2[kx][mt], af1[kx], acc[mt], 0, 0, 0); \
            _Pragma("unroll")                                                \
            for (int kc = 0; kc < 8; ++kc)                                   \
                _Pragma("unroll")                                            \
                for (int mt = 0; mt < 4; ++mt)                               \
                    acc[mt] = __builtin_amdgcn_mfma_f32_16x16x32_bf16(wh2[kc][mt], af2[kc], acc[mt], 0, 0, 0); \
            PACK_STORE(acc, 4, 2048, wro2)                                   \
        }                                                                    \
        if ((unsigned)(tau_ - 2) < TT) { /* L3 */                            \
            f32x4 acc[2];                                                    \
            _Pragma("unroll") for (int mt = 0; mt < 2; ++mt) acc[mt] = bv3[mt]; \
            _Pragma("unroll")                                                \
            for (int kx = 0; kx < 8; ++kx)                                   \
                _Pragma("unroll")                                            \
                for (int mt = 0; mt < 2; ++mt)                               \
                    acc[mt] = __builtin_amdgcn_mfma_f32_16x16x32_bf16(wx3[kx][mt], af2[kx], acc[mt], 0, 0, 0); \
            _Pragma("unroll")                                                \
            for (int kc = 0; kc < 4; ++kc)                                   \
                _Pragma("unroll")                                            \
                for (int mt = 0; mt < 2; ++mt)                               \
                    acc[mt] = __builtin_amdgcn_mfma_f32_16x16x32_bf16(wh3[kc][mt], af3[kc], acc[mt], 0, 0, 0); \
            PACK_STORE(acc, 2, 6144, wro3)                                   \
        }                                                                    \
        if ((unsigned)(tau_ - 3) < TT) { /* L4 */                            \
            f32x4 acc[1];                                                    \
            acc[0] = bv4[0];                                                 \
            _Pragma("unroll")                                                \
            for (int kx = 0; kx < 4; ++kx)                                   \
                acc[0] = __builtin_amdgcn_mfma_f32_16x16x32_bf16(wx4[kx][0], af3[kx], acc[0], 0, 0, 0); \
            _Pragma("unroll")                                                \
            for (int kc = 0; kc < 2; ++kc)                                   \
                acc[0] = __builtin_amdgcn_mfma_f32_16x16x32_bf16(wh4[kc][0], af4[kc], acc[0], 0, 0, 0); \
            ushort2 lo = pk2(fmaxf(acc[0][0], 0.f), fmaxf(acc[0][1], 0.f));  \
            ushort2 hi = pk2(fmaxf(acc[0][2], 0.f), fmaxf(acc[0][3], 0.f));  \
            ushort4 o; o.x = lo.x; o.y = lo.y; o.z = hi.x; o.w = hi.y;       \
            *reinterpret_cast<ushort4*>(&WB[8192 + wro4]) = o;               \
            *reinterpret_cast<ushort4*>(OPP) = o;                            \
            OPP += 2048;                                                     \
        }                                                                    \
        __builtin_amdgcn_s_waitcnt(0xC07F);                                  \
        __builtin_amdgcn_s_barrier();                                        \
    }

#pragma unroll 1
    for (int tau = 0; tau < TT + 3; tau += 2) {
        STEP(tau, 0, 1, xA, xp0, op0)
        STEP(tau + 1, 1, 0, xB, xp1, op1)
    }
#undef STEP
#undef PACK_STORE
}

// ---------------- final dense: out[b] = flat[b,:] . Wd + bd ----------------
// Ht in B-layout (K=64): thread tid reads ushort4 at tid*4 per (s,t) block.
__global__ __launch_bounds__(256) void dense_kernel(const unsigned short* __restrict__ Ht,
                                                    const float* __restrict__ Wd,
                                                    const float* __restrict__ bd,
                                                    float* __restrict__ out) {
    __shared__ float red[16][17];
    const int s = blockIdx.x;
    const int tid = threadIdx.x;
    const int b = (tid >> 1) & 15;
    const int kbase = (tid >> 5) * 8 + (tid & 1) * 4;
    const unsigned short* base = Ht + (size_t)s * TT * 1024 + tid * 4;
    float acc = 0.f;
    for (int t = 0; t < TT; ++t) {
        ushort4 v = *reinterpret_cast<const ushort4*>(base + (size_t)t * 1024);
        const float* wd = &Wd[t * 64 + kbase];
        acc += b2f(v.x) * wd[0] + b2f(v.y) * wd[1] + b2f(v.z) * wd[2] + b2f(v.w) * wd[3];
    }
    red[b][(tid >> 5) * 2 + (tid & 1)] = acc;
    __syncthreads();
    if (tid < 16) {
        float sum = 0.f;
#pragma unroll
        for (int j = 0; j < 16; ++j) sum += red[tid][j];
        out[s * 16 + tid] = sum + bd[0];
    }
}

extern "C" void kernel_launch(void* const* d_in, const int* in_sizes, int n_in,
                              void* d_out, int out_size, void* d_ws, size_t ws_size,
                              hipStream_t stream) {
    (void)in_sizes; (void)n_in; (void)out_size; (void)ws_size;
    const float* x   = (const float*)d_in[0];
    const float* Wx1 = (const float*)d_in[1];
    const float* Wh1 = (const float*)d_in[2];
    const float* b1  = (const float*)d_in[3];
    const float* Wx2 = (const float*)d_in[4];
    const float* Wh2 = (const float*)d_in[5];
    const float* b2  = (const float*)d_in[6];
    const float* Wx3 = (const float*)d_in[7];
    const float* Wh3 = (const float*)d_in[8];
    const float* b3  = (const float*)d_in[9];
    const float* Wx4 = (const float*)d_in[10];
    const float* Wh4 = (const float*)d_in[11];
    const float* b4  = (const float*)d_in[12];
    const float* Wd  = (const float*)d_in[13];
    const float* bd  = (const float*)d_in[14];
    float* out = (float*)d_out;

    char* ws = (char*)d_ws;
    unsigned short* xbT = (unsigned short*)(ws);             // 16.8M
    unsigned short* H4  = (unsigned short*)(ws + 16777216);  // 16.8M

    cvt_tile<<<8192, 256, 0, stream>>>(x, xbT);

    rnn4<<<32, 256, 0, stream>>>(xbT, Wx1, Wh1, b1, Wx2, Wh2, b2,
                                 Wx3, Wh3, b3, Wx4, Wh4, b4, H4);

    dense_kernel<<<32, 256, 0, stream>>>(H4, Wd, bd, out);
}

// Round 14
// 460.239 us; speedup vs baseline: 1.8523x; 1.8523x over previous
//
#include <hip/hip_runtime.h>
#include <hip/hip_bf16.h>

#define BB 512
#define TT 256

typedef __attribute__((ext_vector_type(8))) short bf16x8;
typedef __attribute__((ext_vector_type(4))) float f32x4;

__device__ __forceinline__ unsigned short f2b(float f) {
    union { float f; unsigned u; } v; v.f = f;
    unsigned r = v.u + 0x7FFFu + ((v.u >> 16) & 1u);
    return (unsigned short)(r >> 16);
}
__device__ __forceinline__ float b2f(unsigned short h) {
    union { unsigned u; float f; } v; v.u = ((unsigned)h) << 16;
    return v.f;
}
__device__ __forceinline__ ushort2 pk2(float a, float b) {
    __hip_bfloat162 h = __float22bfloat162_rn(float2{a, b});
    union { __hip_bfloat162 h; ushort2 u; } v; v.h = h; return v.u;
}

// B-layout per (s,t): 16-batch x K shorts, addr(b,k) = (k>>3)*128 + b*8 + (k&7).
// B-frag kc = one b128 at kc*512 + rdo (rdo = quad*128 + l15*8);
// D-tile mt write = ushort4 at wro + mt*256.

// ---------------- fp32 x -> bf16 B-layout tiles ----------------
__global__ __launch_bounds__(256) void cvt_tile(const float* __restrict__ x,
                                                unsigned short* __restrict__ xb) {
    const int blk = blockIdx.x;            // s*256 + t
    const int s = blk >> 8, t = blk & 255;
    const int tid = threadIdx.x;
    const int b = (tid >> 1) & 15;
    const int f0 = (tid >> 5) * 8 + (tid & 1) * 4;
    float4 v = *reinterpret_cast<const float4*>(
        &x[(((size_t)(s * 16 + b) * TT) + t) * 64 + f0]);
    ushort2 lo = pk2(v.x, v.y), hi = pk2(v.z, v.w);
    ushort4 o; o.x = lo.x; o.y = lo.y; o.z = hi.x; o.w = hi.y;
    *reinterpret_cast<ushort4*>(&xb[(size_t)blk * 1024 + tid * 4]) = o;
}

// ---------------- 4-layer skewed fused RNN, wave-specialized ----------------
// 8 waves: w0,w1 = L1(64 cols each)+L4(32 cols each); w2-5 = L2(64 cols);
// w6,7 = L3(64 cols). Shared wreg[48] union (192 VGPR) holds each wave's
// weights; wreg[36..39] double as w0/w1's x parity prefetch regs. Layer l
// processes t = tau-(l-1); all cross-layer traffic via single LDS ping-pong,
// ONE lgkm-only barrier/step. w0+w1 stream h4 to global (1-step lag), 512
// shorts each — r13 bug was w1 alone copying only half the 1024-short block.
__global__ __launch_bounds__(512, 1) void rnn4(
    const unsigned short* __restrict__ Xb,
    const float* __restrict__ Wx1, const float* __restrict__ Wh1, const float* __restrict__ b1,
    const float* __restrict__ Wx2, const float* __restrict__ Wh2, const float* __restrict__ b2,
    const float* __restrict__ Wx3, const float* __restrict__ Wh3, const float* __restrict__ b3,
    const float* __restrict__ Wx4, const float* __restrict__ Wh4, const float* __restrict__ b4,
    unsigned short* __restrict__ H4) {
    const int tid = threadIdx.x;
    const int s = blockIdx.x;
    const int w = tid >> 6;
    const int lane = tid & 63;
    const int l15 = lane & 15;
    const int quad = lane >> 4;
    const int rdo = quad * 128 + l15 * 8;

    // LDS: h1[0,2048) h2[2048,6144) h3[6144,8192) h4[8192,9216) per parity
    __shared__ __align__(16) unsigned short hall[2][9216];

    bf16x8 wreg[48];
    ushort4 bvp[6];

#define LOADW(BASE, WP, H_, CB, KC_, MT_)                                          \
    _Pragma("unroll")                                                              \
    for (int mt = 0; mt < MT_; ++mt) {                                             \
        int m = (CB) + mt * 16 + l15;                                              \
        _Pragma("unroll")                                                          \
        for (int kc = 0; kc < KC_; ++kc)                                           \
            _Pragma("unroll")                                                      \
            for (int j = 0; j < 8; ++j)                                            \
                wreg[(BASE) + kc * MT_ + mt][j] =                                  \
                    (short)f2b(WP[(kc * 32 + quad * 8 + j) * H_ + m]);             \
    }
#define LOADBV(OFF, BP, CB, MT_)                                                   \
    _Pragma("unroll")                                                              \
    for (int mt = 0; mt < MT_; ++mt) {                                             \
        const float* p = (BP) + (CB) + mt * 16 + quad * 4;                         \
        ushort4 u; u.x = f2b(p[0]); u.y = f2b(p[1]); u.z = f2b(p[2]); u.w = f2b(p[3]); \
        bvp[(OFF) + mt] = u;                                                       \
    }

    if (w < 2) {
        LOADW(0,  Wh1, 128, w * 64, 4, 4)
        LOADW(16, Wx1, 128, w * 64, 2, 4)
        LOADW(24, Wh4, 64,  w * 32, 2, 2)
        LOADW(28, Wx4, 64,  w * 32, 4, 2)
        LOADBV(0, b1, w * 64, 4)
        LOADBV(4, b4, w * 32, 2)
    } else if (w < 6) {
        LOADW(0,  Wh2, 256, (w - 2) * 64, 8, 4)
        LOADW(32, Wx2, 256, (w - 2) * 64, 4, 4)
        LOADBV(0, b2, (w - 2) * 64, 4)
    } else {
        LOADW(0,  Wh3, 128, (w - 6) * 64, 4, 4)
        LOADW(16, Wx3, 128, (w - 6) * 64, 8, 4)
        LOADBV(0, b3, (w - 6) * 64, 4)
    }
#undef LOADW
#undef LOADBV

    for (int i = tid; i < 2 * 9216; i += 512) (&hall[0][0])[i] = 0;

    const unsigned short* Xs = Xb + (size_t)s * TT * 1024;
    unsigned short* H4s = H4 + (size_t)s * TT * 1024;

    // x parity prefetch into wreg[36..39]: [36,37] even t, [38,39] odd t
    if (w < 2) {
#pragma unroll
        for (int kx = 0; kx < 2; ++kx) {
            wreg[36 + kx] = *reinterpret_cast<const bf16x8*>(&Xs[kx * 512 + rdo]);
            wreg[38 + kx] = *reinterpret_cast<const bf16x8*>(&Xs[1024 + kx * 512 + rdo]);
        }
    }
    __syncthreads();

    const unsigned short* xp0 = Xs + 2 * 1024 + rdo;   // even prefetch target
    const unsigned short* xp1 = Xs + 3 * 1024 + rdo;   // odd
    // h4 copy: w0 covers shorts [0,512), w1 covers [512,1024) of each block
    unsigned short* opc_e = H4s + w * 512 + lane * 8;          // t4 even
    unsigned short* opc_o = H4s + 1024 + w * 512 + lane * 8;   // t4 odd

    const int wro1 = (w * 8 + (quad >> 1)) * 128 + l15 * 8 + (quad & 1) * 4;
    const int wro4 = 8192 + (w * 4 + (quad >> 1)) * 128 + l15 * 8 + (quad & 1) * 4;
    const int wro2 = 2048 + ((w - 2) * 8 + (quad >> 1)) * 128 + l15 * 8 + (quad & 1) * 4;
    const int wro3 = 6144 + ((w - 6) * 8 + (quad >> 1)) * 128 + l15 * 8 + (quad & 1) * 4;

#define ACCI(ACC, N_, OFF)                                                         \
    _Pragma("unroll")                                                              \
    for (int mt = 0; mt < N_; ++mt) {                                              \
        ACC[mt][0] = b2f(bvp[(OFF) + mt].x); ACC[mt][1] = b2f(bvp[(OFF) + mt].y);  \
        ACC[mt][2] = b2f(bvp[(OFF) + mt].z); ACC[mt][3] = b2f(bvp[(OFF) + mt].w);  \
    }
#define PACKST(ACC, N_, DST, WRO)                                                  \
    _Pragma("unroll")                                                              \
    for (int mt = 0; mt < N_; ++mt) {                                              \
        ushort2 lo = pk2(fmaxf(ACC[mt][0], 0.f), fmaxf(ACC[mt][1], 0.f));          \
        ushort2 hi = pk2(fmaxf(ACC[mt][2], 0.f), fmaxf(ACC[mt][3], 0.f));          \
        ushort4 o; o.x = lo.x; o.y = lo.y; o.z = hi.x; o.w = hi.y;                 \
        *reinterpret_cast<ushort4*>(&DST[(WRO) + mt * 256]) = o;                   \
    }

#define STEP(TAU_, RP_, WP_, XAB, XPP, OPC)                                        \
    {                                                                              \
        const int tau_ = (TAU_);                                                   \
        const unsigned short* RB = &hall[RP_][0];                                  \
        unsigned short* WB = &hall[WP_][0];                                        \
        if (w < 2) {                                                               \
            if ((unsigned)tau_ < TT) { /* L1 */                                    \
                f32x4 acc[4];                                                      \
                ACCI(acc, 4, 0)                                                    \
                _Pragma("unroll")                                                  \
                for (int kx = 0; kx < 2; ++kx)                                     \
                    _Pragma("unroll")                                              \
                    for (int mt = 0; mt < 4; ++mt)                                 \
                        acc[mt] = __builtin_amdgcn_mfma_f32_16x16x32_bf16(         \
                            wreg[16 + kx * 4 + mt], wreg[(XAB) + kx], acc[mt], 0, 0, 0); \
                if (tau_ + 2 < TT) {                                               \
                    wreg[(XAB) + 0] = *reinterpret_cast<const bf16x8*>(XPP);       \
                    wreg[(XAB) + 1] = *reinterpret_cast<const bf16x8*>(XPP + 512); \
                    XPP += 2048;                                                   \
                }                                                                  \
                _Pragma("unroll")                                                  \
                for (int kc = 0; kc < 4; ++kc) {                                   \
                    bf16x8 af = *reinterpret_cast<const bf16x8*>(&RB[rdo + kc * 512]); \
                    _Pragma("unroll")                                              \
                    for (int mt = 0; mt < 4; ++mt)                                 \
                        acc[mt] = __builtin_amdgcn_mfma_f32_16x16x32_bf16(         \
                            wreg[kc * 4 + mt], af, acc[mt], 0, 0, 0);              \
                }                                                                  \
                PACKST(acc, 4, WB, wro1)                                           \
            }                                                                      \
            if ((unsigned)(tau_ - 3) < TT) { /* L4 */                              \
                f32x4 acc[2];                                                      \
                ACCI(acc, 2, 4)                                                    \
                _Pragma("unroll")                                                  \
                for (int kx = 0; kx < 4; ++kx) {                                   \
                    bf16x8 af = *reinterpret_cast<const bf16x8*>(&RB[6144 + rdo + kx * 512]); \
                    _Pragma("unroll")                                              \
                    for (int mt = 0; mt < 2; ++mt)                                 \
                        acc[mt] = __builtin_amdgcn_mfma_f32_16x16x32_bf16(         \
                            wreg[28 + kx * 2 + mt], af, acc[mt], 0, 0, 0);         \
                }                                                                  \
                _Pragma("unroll")                                                  \
                for (int kc = 0; kc < 2; ++kc) {                                   \
                    bf16x8 af = *reinterpret_cast<const bf16x8*>(&RB[8192 + rdo + kc * 512]); \
                    _Pragma("unroll")                                              \
                    for (int mt = 0; mt < 2; ++mt)                                 \
                        acc[mt] = __builtin_amdgcn_mfma_f32_16x16x32_bf16(         \
                            wreg[24 + kc * 2 + mt], af, acc[mt], 0, 0, 0);         \
                }                                                                  \
                PACKST(acc, 2, WB, wro4)                                           \
            }                                                                      \
            if ((unsigned)(tau_ - 4) < TT) { /* h4 -> global, w0+w1 halves */      \
                uint4 v = *reinterpret_cast<const uint4*>(&RB[8192 + w * 512 + lane * 8]); \
                *reinterpret_cast<uint4*>(OPC) = v;                                \
                OPC += 2048;                                                       \
            }                                                                      \
        } else if (w < 6) {                                                        \
            if ((unsigned)(tau_ - 1) < TT) { /* L2 */                              \
                f32x4 acc[4];                                                      \
                ACCI(acc, 4, 0)                                                    \
                _Pragma("unroll")                                                  \
                for (int kx = 0; kx < 4; ++kx) {                                   \
                    bf16x8 af = *reinterpret_cast<const bf16x8*>(&RB[rdo + kx * 512]); \
                    _Pragma("unroll")                                              \
                    for (int mt = 0; mt < 4; ++mt)                                 \
                        acc[mt] = __builtin_amdgcn_mfma_f32_16x16x32_bf16(         \
                            wreg[32 + kx * 4 + mt], af, acc[mt], 0, 0, 0);         \
                }                                                                  \
                _Pragma("unroll")                                                  \
                for (int kc = 0; kc < 8; ++kc) {                                   \
                    bf16x8 af = *reinterpret_cast<const bf16x8*>(&RB[2048 + rdo + kc * 512]); \
                    _Pragma("unroll")                                              \
                    for (int mt = 0; mt < 4; ++mt)                                 \
                        acc[mt] = __builtin_amdgcn_mfma_f32_16x16x32_bf16(         \
                            wreg[kc * 4 + mt], af, acc[mt], 0, 0, 0);              \
                }                                                                  \
                PACKST(acc, 4, WB, wro2)                                           \
            }                                                                      \
        } else {                                                                   \
            if ((unsigned)(tau_ - 2) < TT) { /* L3 */                              \
                f32x4 acc[4];                                                      \
                ACCI(acc, 4, 0)                                                    \
                _Pragma("unroll")                                                  \
                for (int kx = 0; kx < 8; ++kx) {                                   \
                    bf16x8 af = *reinterpret_cast<const bf16x8*>(&RB[2048 + rdo + kx * 512]); \
                    _Pragma("unroll")                                              \
                    for (int mt = 0; mt < 4; ++mt)                                 \
                        acc[mt] = __builtin_amdgcn_mfma_f32_16x16x32_bf16(         \
                            wreg[16 + kx * 4 + mt], af, acc[mt], 0, 0, 0);         \
                }                                                                  \
                _Pragma("unroll")                                                  \
                for (int kc = 0; kc < 4; ++kc) {                                   \
                    bf16x8 af = *reinterpret_cast<const bf16x8*>(&RB[6144 + rdo + kc * 512]); \
                    _Pragma("unroll")                                              \
                    for (int mt = 0; mt < 4; ++mt)                                 \
                        acc[mt] = __builtin_amdgcn_mfma_f32_16x16x32_bf16(         \
                            wreg[kc * 4 + mt], af, acc[mt], 0, 0, 0);              \
                }                                                                  \
                PACKST(acc, 4, WB, wro3)                                           \
            }                                                                      \
        }                                                                          \
        __builtin_amdgcn_s_waitcnt(0xC07F);                                        \
        __builtin_amdgcn_s_barrier();                                              \
    }

#pragma unroll 1
    for (int tau = 0; tau < TT + 3; tau += 2) {
        STEP(tau, 0, 1, 36, xp0, opc_e)
        STEP(tau + 1, 1, 0, 38, xp1, opc_o)
    }
#undef STEP
#undef ACCI
#undef PACKST
}

// ---------------- final dense: out[b] = flat[b,:] . Wd + bd ----------------
__global__ __launch_bounds__(256) void dense_kernel(const unsigned short* __restrict__ Ht,
                                                    const float* __restrict__ Wd,
                                                    const float* __restrict__ bd,
                                                    float* __restrict__ out) {
    __shared__ float red[16][17];
    const int s = blockIdx.x;
    const int tid = threadIdx.x;
    const int b = (tid >> 1) & 15;
    const int kbase = (tid >> 5) * 8 + (tid & 1) * 4;
    const unsigned short* base = Ht + (size_t)s * TT * 1024 + tid * 4;
    float acc = 0.f;
    for (int t = 0; t < TT; ++t) {
        ushort4 v = *reinterpret_cast<const ushort4*>(base + (size_t)t * 1024);
        const float* wd = &Wd[t * 64 + kbase];
        acc += b2f(v.x) * wd[0] + b2f(v.y) * wd[1] + b2f(v.z) * wd[2] + b2f(v.w) * wd[3];
    }
    red[b][(tid >> 5) * 2 + (tid & 1)] = acc;
    __syncthreads();
    if (tid < 16) {
        float sum = 0.f;
#pragma unroll
        for (int j = 0; j < 16; ++j) sum += red[tid][j];
        out[s * 16 + tid] = sum + bd[0];
    }
}

extern "C" void kernel_launch(void* const* d_in, const int* in_sizes, int n_in,
                              void* d_out, int out_size, void* d_ws, size_t ws_size,
                              hipStream_t stream) {
    (void)in_sizes; (void)n_in; (void)out_size; (void)ws_size;
    const float* x   = (const float*)d_in[0];
    const float* Wx1 = (const float*)d_in[1];
    const float* Wh1 = (const float*)d_in[2];
    const float* b1  = (const float*)d_in[3];
    const float* Wx2 = (const float*)d_in[4];
    const float* Wh2 = (const float*)d_in[5];
    const float* b2  = (const float*)d_in[6];
    const float* Wx3 = (const float*)d_in[7];
    const float* Wh3 = (const float*)d_in[8];
    const float* b3  = (const float*)d_in[9];
    const float* Wx4 = (const float*)d_in[10];
    const float* Wh4 = (const float*)d_in[11];
    const float* b4  = (const float*)d_in[12];
    const float* Wd  = (const float*)d_in[13];
    const float* bd  = (const float*)d_in[14];
    float* out = (float*)d_out;

    char* ws = (char*)d_ws;
    unsigned short* xbT = (unsigned short*)(ws);             // 16.8M
    unsigned short* H4  = (unsigned short*)(ws + 16777216);  // 16.8M

    cvt_tile<<<8192, 256, 0, stream>>>(x, xbT);

    rnn4<<<32, 512, 0, stream>>>(xbT, Wx1, Wh1, b1, Wx2, Wh2, b2,
                                 Wx3, Wh3, b3, Wx4, Wh4, b4, H4);

    dense_kernel<<<32, 256, 0, stream>>>(H4, Wd, bd, out);
}

// Round 15
// 439.322 us; speedup vs baseline: 1.9405x; 1.0476x over previous
//
#include <hip/hip_runtime.h>
#include <hip/hip_bf16.h>

#define BB 512
#define TT 256

typedef __attribute__((ext_vector_type(8))) short bf16x8;
typedef __attribute__((ext_vector_type(4))) float f32x4;

__device__ __forceinline__ unsigned short f2b(float f) {
    union { float f; unsigned u; } v; v.f = f;
    unsigned r = v.u + 0x7FFFu + ((v.u >> 16) & 1u);
    return (unsigned short)(r >> 16);
}
__device__ __forceinline__ float b2f(unsigned short h) {
    union { unsigned u; float f; } v; v.u = ((unsigned)h) << 16;
    return v.f;
}
__device__ __forceinline__ ushort2 pk2(float a, float b) {
    __hip_bfloat162 h = __float22bfloat162_rn(float2{a, b});
    union { __hip_bfloat162 h; ushort2 u; } v; v.h = h; return v.u;
}

// B-layout per (s,t): 16-batch x K shorts, addr(b,k) = (k>>3)*128 + b*8 + (k&7).
// B-frag kc = one b128 at kc*512 + rdo (rdo = quad*128 + l15*8);
// D-tile mt write = ushort4 at wro + mt*256.

// ---------------- fp32 x -> bf16 B-layout tiles ----------------
__global__ __launch_bounds__(256) void cvt_tile(const float* __restrict__ x,
                                                unsigned short* __restrict__ xb) {
    const int blk = blockIdx.x;            // s*256 + t
    const int s = blk >> 8, t = blk & 255;
    const int tid = threadIdx.x;
    const int b = (tid >> 1) & 15;
    const int f0 = (tid >> 5) * 8 + (tid & 1) * 4;
    float4 v = *reinterpret_cast<const float4*>(
        &x[(((size_t)(s * 16 + b) * TT) + t) * 64 + f0]);
    ushort2 lo = pk2(v.x, v.y), hi = pk2(v.z, v.w);
    ushort4 o; o.x = lo.x; o.y = lo.y; o.z = hi.x; o.w = hi.y;
    *reinterpret_cast<ushort4*>(&xb[(size_t)blk * 1024 + tid * 4]) = o;
}

// ---------------- 4-layer skewed fused RNN, wave-specialized ----------------
// 8 waves: w0,w1 = L1(64 cols)+L4(32 cols); w2-5 = L2(64 cols); w6,7 = L3.
// wreg[48] (192 VGPR) holds the wave's weights; wreg[36..39] double as w0/w1
// x parity prefetch. Bias lives in fp32 regs and enters as the C operand of
// each layer's FIRST input-MFMA (no acc-init copies, bit-identical: bias was
// the init value). L4 stores h4 to global straight from its pack registers.
// waves_per_eu(2,2): pin 256 regs/wave — r14's 128-VGPR allocation forced
// AGPR/scratch churn (~740 VALU cyc/SIMD/step).
__global__ __launch_bounds__(512) __attribute__((amdgpu_waves_per_eu(2, 2))) void rnn4(
    const unsigned short* __restrict__ Xb,
    const float* __restrict__ Wx1, const float* __restrict__ Wh1, const float* __restrict__ b1,
    const float* __restrict__ Wx2, const float* __restrict__ Wh2, const float* __restrict__ b2,
    const float* __restrict__ Wx3, const float* __restrict__ Wh3, const float* __restrict__ b3,
    const float* __restrict__ Wx4, const float* __restrict__ Wh4, const float* __restrict__ b4,
    unsigned short* __restrict__ H4) {
    const int tid = threadIdx.x;
    const int s = blockIdx.x;
    const int w = tid >> 6;
    const int lane = tid & 63;
    const int l15 = lane & 15;
    const int quad = lane >> 4;
    const int rdo = quad * 128 + l15 * 8;

    // LDS: h1[0,2048) h2[2048,6144) h3[6144,8192) h4[8192,9216) per parity
    __shared__ __align__(16) unsigned short hall[2][9216];

    bf16x8 wreg[48];
    f32x4 bvv[6];

#define LOADW(BASE, WP, H_, CB, KC_, MT_)                                          \
    _Pragma("unroll")                                                              \
    for (int mt = 0; mt < MT_; ++mt) {                                             \
        int m = (CB) + mt * 16 + l15;                                              \
        _Pragma("unroll")                                                          \
        for (int kc = 0; kc < KC_; ++kc)                                           \
            _Pragma("unroll")                                                      \
            for (int j = 0; j < 8; ++j)                                            \
                wreg[(BASE) + kc * MT_ + mt][j] =                                  \
                    (short)f2b(WP[(kc * 32 + quad * 8 + j) * H_ + m]);             \
    }
#define LOADBF(OFF, BP, CB, MT_)                                                   \
    _Pragma("unroll")                                                              \
    for (int mt = 0; mt < MT_; ++mt) {                                             \
        float4 t4v = *reinterpret_cast<const float4*>((BP) + (CB) + mt * 16 + quad * 4); \
        bvv[(OFF) + mt][0] = t4v.x; bvv[(OFF) + mt][1] = t4v.y;                    \
        bvv[(OFF) + mt][2] = t4v.z; bvv[(OFF) + mt][3] = t4v.w;                    \
    }

    if (w < 2) {
        LOADW(0,  Wh1, 128, w * 64, 4, 4)
        LOADW(16, Wx1, 128, w * 64, 2, 4)
        LOADW(24, Wh4, 64,  w * 32, 2, 2)
        LOADW(28, Wx4, 64,  w * 32, 4, 2)
        LOADBF(0, b1, w * 64, 4)
        LOADBF(4, b4, w * 32, 2)
    } else if (w < 6) {
        LOADW(0,  Wh2, 256, (w - 2) * 64, 8, 4)
        LOADW(32, Wx2, 256, (w - 2) * 64, 4, 4)
        LOADBF(0, b2, (w - 2) * 64, 4)
    } else {
        LOADW(0,  Wh3, 128, (w - 6) * 64, 4, 4)
        LOADW(16, Wx3, 128, (w - 6) * 64, 8, 4)
        LOADBF(0, b3, (w - 6) * 64, 4)
    }
#undef LOADW
#undef LOADBF

    for (int i = tid; i < 2 * 9216; i += 512) (&hall[0][0])[i] = 0;

    const unsigned short* Xs = Xb + (size_t)s * TT * 1024;
    unsigned short* H4s = H4 + (size_t)s * TT * 1024;

    // x parity prefetch into wreg[36..39]: [36,37] even t, [38,39] odd t
    if (w < 2) {
#pragma unroll
        for (int kx = 0; kx < 2; ++kx) {
            wreg[36 + kx] = *reinterpret_cast<const bf16x8*>(&Xs[kx * 512 + rdo]);
            wreg[38 + kx] = *reinterpret_cast<const bf16x8*>(&Xs[1024 + kx * 512 + rdo]);
        }
    }
    __syncthreads();

    const unsigned short* xp0 = Xs + 2 * 1024 + rdo;   // even prefetch target
    const unsigned short* xp1 = Xs + 3 * 1024 + rdo;   // odd

    const int wro1 = (w * 8 + (quad >> 1)) * 128 + l15 * 8 + (quad & 1) * 4;
    const int wro4 = 8192 + (w * 4 + (quad >> 1)) * 128 + l15 * 8 + (quad & 1) * 4;
    const int wro2 = 2048 + ((w - 2) * 8 + (quad >> 1)) * 128 + l15 * 8 + (quad & 1) * 4;
    const int wro3 = 6144 + ((w - 6) * 8 + (quad >> 1)) * 128 + l15 * 8 + (quad & 1) * 4;

    // L4 direct global store: even-macro (tau even) stores t4 = tau-3 (odd);
    // odd-macro stores even t4. g-offset = wro4 - 8192 (+ mt*256).
    unsigned short* op_e = H4s + 1024 + (wro4 - 8192);  // first even-macro t4 = 1
    unsigned short* op_o = H4s + (wro4 - 8192);         // first odd-macro  t4 = 0

#define PACKMK(ACC_MT)                                                             \
    ushort2 lo = pk2(fmaxf((ACC_MT)[0], 0.f), fmaxf((ACC_MT)[1], 0.f));            \
    ushort2 hi = pk2(fmaxf((ACC_MT)[2], 0.f), fmaxf((ACC_MT)[3], 0.f));            \
    ushort4 o; o.x = lo.x; o.y = lo.y; o.z = hi.x; o.w = hi.y;

#define STEP(TAU_, RP_, WP_, XAB, XPP, OPP)                                        \
    {                                                                              \
        const int tau_ = (TAU_);                                                   \
        const unsigned short* RB = &hall[RP_][0];                                  \
        unsigned short* WB = &hall[WP_][0];                                        \
        if (w < 2) {                                                               \
            if ((unsigned)tau_ < TT) { /* L1 */                                    \
                f32x4 acc[4];                                                      \
                _Pragma("unroll")                                                  \
                for (int mt = 0; mt < 4; ++mt)                                     \
                    acc[mt] = __builtin_amdgcn_mfma_f32_16x16x32_bf16(             \
                        wreg[16 + mt], wreg[(XAB) + 0], bvv[mt], 0, 0, 0);         \
                _Pragma("unroll")                                                  \
                for (int mt = 0; mt < 4; ++mt)                                     \
                    acc[mt] = __builtin_amdgcn_mfma_f32_16x16x32_bf16(             \
                        wreg[20 + mt], wreg[(XAB) + 1], acc[mt], 0, 0, 0);         \
                if (tau_ + 2 < TT) {                                               \
                    wreg[(XAB) + 0] = *reinterpret_cast<const bf16x8*>(XPP);       \
                    wreg[(XAB) + 1] = *reinterpret_cast<const bf16x8*>(XPP + 512); \
                    XPP += 2048;                                                   \
                }                                                                  \
                _Pragma("unroll")                                                  \
                for (int kc = 0; kc < 4; ++kc) {                                   \
                    bf16x8 af = *reinterpret_cast<const bf16x8*>(&RB[rdo + kc * 512]); \
                    _Pragma("unroll")                                              \
                    for (int mt = 0; mt < 4; ++mt)                                 \
                        acc[mt] = __builtin_amdgcn_mfma_f32_16x16x32_bf16(         \
                            wreg[kc * 4 + mt], af, acc[mt], 0, 0, 0);              \
                }                                                                  \
                _Pragma("unroll")                                                  \
                for (int mt = 0; mt < 4; ++mt) {                                   \
                    PACKMK(acc[mt])                                                \
                    *reinterpret_cast<ushort4*>(&WB[wro1 + mt * 256]) = o;         \
                }                                                                  \
            }                                                                      \
            if ((unsigned)(tau_ - 3) < TT) { /* L4 */                              \
                f32x4 acc[2];                                                      \
                {                                                                  \
                    bf16x8 af0 = *reinterpret_cast<const bf16x8*>(&RB[6144 + rdo]); \
                    _Pragma("unroll")                                              \
                    for (int mt = 0; mt < 2; ++mt)                                 \
                        acc[mt] = __builtin_amdgcn_mfma_f32_16x16x32_bf16(         \
                            wreg[28 + mt], af0, bvv[4 + mt], 0, 0, 0);             \
                }                                                                  \
                _Pragma("unroll")                                                  \
                for (int kx = 1; kx < 4; ++kx) {                                   \
                    bf16x8 af = *reinterpret_cast<const bf16x8*>(&RB[6144 + rdo + kx * 512]); \
                    _Pragma("unroll")                                              \
                    for (int mt = 0; mt < 2; ++mt)                                 \
                        acc[mt] = __builtin_amdgcn_mfma_f32_16x16x32_bf16(         \
                            wreg[28 + kx * 2 + mt], af, acc[mt], 0, 0, 0);         \
                }                                                                  \
                _Pragma("unroll")                                                  \
                for (int kc = 0; kc < 2; ++kc) {                                   \
                    bf16x8 af = *reinterpret_cast<const bf16x8*>(&RB[8192 + rdo + kc * 512]); \
                    _Pragma("unroll")                                              \
                    for (int mt = 0; mt < 2; ++mt)                                 \
                        acc[mt] = __builtin_amdgcn_mfma_f32_16x16x32_bf16(         \
                            wreg[24 + kc * 2 + mt], af, acc[mt], 0, 0, 0);         \
                }                                                                  \
                _Pragma("unroll")                                                  \
                for (int mt = 0; mt < 2; ++mt) {                                   \
                    PACKMK(acc[mt])                                                \
                    *reinterpret_cast<ushort4*>(&WB[wro4 + mt * 256]) = o;         \
                    *reinterpret_cast<ushort4*>(OPP + mt * 256) = o;               \
                }                                                                  \
                OPP += 2048;                                                       \
            }                                                                      \
        } else if (w < 6) {                                                        \
            if ((unsigned)(tau_ - 1) < TT) { /* L2 */                              \
                f32x4 acc[4];                                                      \
                {                                                                  \
                    bf16x8 af0 = *reinterpret_cast<const bf16x8*>(&RB[rdo]);       \
                    _Pragma("unroll")                                              \
                    for (int mt = 0; mt < 4; ++mt)                                 \
                        acc[mt] = __builtin_amdgcn_mfma_f32_16x16x32_bf16(         \
                            wreg[32 + mt], af0, bvv[mt], 0, 0, 0);                 \
                }                                                                  \
                _Pragma("unroll")                                                  \
                for (int kx = 1; kx < 4; ++kx) {                                   \
                    bf16x8 af = *reinterpret_cast<const bf16x8*>(&RB[rdo + kx * 512]); \
                    _Pragma("unroll")                                              \
                    for (int mt = 0; mt < 4; ++mt)                                 \
                        acc[mt] = __builtin_amdgcn_mfma_f32_16x16x32_bf16(         \
                            wreg[32 + kx * 4 + mt], af, acc[mt], 0, 0, 0);         \
                }                                                                  \
                _Pragma("unroll")                                                  \
                for (int kc = 0; kc < 8; ++kc) {                                   \
                    bf16x8 af = *reinterpret_cast<const bf16x8*>(&RB[2048 + rdo + kc * 512]); \
                    _Pragma("unroll")                                              \
                    for (int mt = 0; mt < 4; ++mt)                                 \
                        acc[mt] = __builtin_amdgcn_mfma_f32_16x16x32_bf16(         \
                            wreg[kc * 4 + mt], af, acc[mt], 0, 0, 0);              \
                }                                                                  \
                _Pragma("unroll")                                                  \
                for (int mt = 0; mt < 4; ++mt) {                                   \
                    PACKMK(acc[mt])                                                \
                    *reinterpret_cast<ushort4*>(&WB[wro2 + mt * 256]) = o;         \
                }                                                                  \
            }                                                                      \
        } else {                                                                   \
            if ((unsigned)(tau_ - 2) < TT) { /* L3 */                              \
                f32x4 acc[4];                                                      \
                {                                                                  \
                    bf16x8 af0 = *reinterpret_cast<const bf16x8*>(&RB[2048 + rdo]); \
                    _Pragma("unroll")                                              \
                    for (int mt = 0; mt < 4; ++mt)                                 \
                        acc[mt] = __builtin_amdgcn_mfma_f32_16x16x32_bf16(         \
                            wreg[16 + mt], af0, bvv[mt], 0, 0, 0);                 \
                }                                                                  \
                _Pragma("unroll")                                                  \
                for (int kx = 1; kx < 8; ++kx) {                                   \
                    bf16x8 af = *reinterpret_cast<const bf16x8*>(&RB[2048 + rdo + kx * 512]); \
                    _Pragma("unroll")                                              \
                    for (int mt = 0; mt < 4; ++mt)                                 \
                        acc[mt] = __builtin_amdgcn_mfma_f32_16x16x32_bf16(         \
                            wreg[16 + kx * 4 + mt], af, acc[mt], 0, 0, 0);         \
                }                                                                  \
                _Pragma("unroll")                                                  \
                for (int kc = 0; kc < 4; ++kc) {                                   \
                    bf16x8 af = *reinterpret_cast<const bf16x8*>(&RB[6144 + rdo + kc * 512]); \
                    _Pragma("unroll")                                              \
                    for (int mt = 0; mt < 4; ++mt)                                 \
                        acc[mt] = __builtin_amdgcn_mfma_f32_16x16x32_bf16(         \
                            wreg[kc * 4 + mt], af, acc[mt], 0, 0, 0);              \
                }                                                                  \
                _Pragma("unroll")                                                  \
                for (int mt = 0; mt < 4; ++mt) {                                   \
                    PACKMK(acc[mt])                                                \
                    *reinterpret_cast<ushort4*>(&WB[wro3 + mt * 256]) = o;         \
                }                                                                  \
            }                                                                      \
        }                                                                          \
        __builtin_amdgcn_s_waitcnt(0xC07F);                                        \
        __builtin_amdgcn_s_barrier();                                              \
    }

#pragma unroll 1
    for (int tau = 0; tau < TT + 3; tau += 2) {
        STEP(tau, 0, 1, 36, xp0, op_e)
        STEP(tau + 1, 1, 0, 38, xp1, op_o)
    }
#undef STEP
#undef PACKMK
}

// ---------------- final dense: out[b] = flat[b,:] . Wd + bd ----------------
__global__ __launch_bounds__(256) void dense_kernel(const unsigned short* __restrict__ Ht,
                                                    const float* __restrict__ Wd,
                                                    const float* __restrict__ bd,
                                                    float* __restrict__ out) {
    __shared__ float red[16][17];
    const int s = blockIdx.x;
    const int tid = threadIdx.x;
    const int b = (tid >> 1) & 15;
    const int kbase = (tid >> 5) * 8 + (tid & 1) * 4;
    const unsigned short* base = Ht + (size_t)s * TT * 1024 + tid * 4;
    float acc = 0.f;
    for (int t = 0; t < TT; ++t) {
        ushort4 v = *reinterpret_cast<const ushort4*>(base + (size_t)t * 1024);
        const float* wd = &Wd[t * 64 + kbase];
        acc += b2f(v.x) * wd[0] + b2f(v.y) * wd[1] + b2f(v.z) * wd[2] + b2f(v.w) * wd[3];
    }
    red[b][(tid >> 5) * 2 + (tid & 1)] = acc;
    __syncthreads();
    if (tid < 16) {
        float sum = 0.f;
#pragma unroll
        for (int j = 0; j < 16; ++j) sum += red[tid][j];
        out[s * 16 + tid] = sum + bd[0];
    }
}

extern "C" void kernel_launch(void* const* d_in, const int* in_sizes, int n_in,
                              void* d_out, int out_size, void* d_ws, size_t ws_size,
                              hipStream_t stream) {
    (void)in_sizes; (void)n_in; (void)out_size; (void)ws_size;
    const float* x   = (const float*)d_in[0];
    const float* Wx1 = (const float*)d_in[1];
    const float* Wh1 = (const float*)d_in[2];
    const float* b1  = (const float*)d_in[3];
    const float* Wx2 = (const float*)d_in[4];
    const float* Wh2 = (const float*)d_in[5];
    const float* b2  = (const float*)d_in[6];
    const float* Wx3 = (const float*)d_in[7];
    const float* Wh3 = (const float*)d_in[8];
    const float* b3  = (const float*)d_in[9];
    const float* Wx4 = (const float*)d_in[10];
    const float* Wh4 = (const float*)d_in[11];
    const float* b4  = (const float*)d_in[12];
    const float* Wd  = (const float*)d_in[13];
    const float* bd  = (const float*)d_in[14];
    float* out = (float*)d_out;

    char* ws = (char*)d_ws;
    unsigned short* xbT = (unsigned short*)(ws);             // 16.8M
    unsigned short* H4  = (unsigned short*)(ws + 16777216);  // 16.8M

    cvt_tile<<<8192, 256, 0, stream>>>(x, xbT);

    rnn4<<<32, 512, 0, stream>>>(xbT, Wx1, Wh1, b1, Wx2, Wh2, b2,
                                 Wx3, Wh3, b3, Wx4, Wh4, b4, H4);

    dense_kernel<<<32, 256, 0, stream>>>(H4, Wd, bd, out);
}